// Round 5
// baseline (2026.461 us; speedup 1.0000x reference)
//
#include <hip/hip_runtime.h>

// ---------------- problem constants ----------------
#define B_    2
#define S_    2048
#define HID_  3584
#define NH_   16
#define NKV_  8
#define HD_   256
#define DQ_   (NH_ * HD_)    // 4096
#define DKV_  (NKV_ * HD_)   // 2048

static constexpr float SCALE_ = 0.0625f;   // 256^-0.5
static constexpr float NEGBIG = -1.0e9f;

typedef __bf16 bf16_t;
typedef __bf16 bf16x8 __attribute__((ext_vector_type(8)));
typedef __bf16 bf16x4 __attribute__((ext_vector_type(4)));
typedef float  f32x4  __attribute__((ext_vector_type(4)));

__device__ inline bf16x8 pack_bf16x8(float4 a, float4 b) {
  bf16x8 r;
  r[0] = (bf16_t)a.x; r[1] = (bf16_t)a.y; r[2] = (bf16_t)a.z; r[3] = (bf16_t)a.w;
  r[4] = (bf16_t)b.x; r[5] = (bf16_t)b.y; r[6] = (bf16_t)b.z; r[7] = (bf16_t)b.w;
  return r;
}

// ---------------- GEMM: C[m][n] = sum_k A[m][k] * Bt[n][k] ----------------
// 128x128 tile, BK=32, 256 threads (4 waves, each 64x64 = 4x4 frags of 16x16x32).
// Weights (Bt) are f32, converted to bf16 during staging.
// MODE 0: A = bf16, OUT = f32, plain row-major [M][N]       (o-proj -> d_out)
// MODE 1: A = f32,  OUT = bf16, relayout to (B, nh, S, HD)  (Q, K projections)
// MODE 2: A = f32,  OUT = bf16, transpose to (B, NKV, HD, S) (V projection)
template<int MODE>
__global__ __launch_bounds__(256) void gemm_f32w(const void* __restrict__ Av,
                                                 const float* __restrict__ Bt,
                                                 void* __restrict__ outv,
                                                 int M, int N, int K, int nh) {
  __shared__ __align__(16) bf16_t As[128][40];  // +8 pad: conflict-free ds_read_b128
  __shared__ __align__(16) bf16_t Bs[128][40];
  const int t = threadIdx.x;
  const int lane = t & 63, wave = t >> 6;
  const int wr = wave >> 1, wc = wave & 1;
  const int lr = lane & 15, lg = lane >> 4;
  const size_t m0 = (size_t)blockIdx.y * 128, n0 = (size_t)blockIdx.x * 128;
  const int srow = t >> 1, scol = (t & 1) * 16;   // each thread stages 16 elems of one row

  const float*  bp  = Bt + (n0 + srow) * (size_t)K + scol;
  const float*  apf = (MODE != 0) ? ((const float*)Av + (m0 + srow) * (size_t)K + scol) : nullptr;
  const bf16_t* aph = (MODE == 0) ? ((const bf16_t*)Av + (m0 + srow) * (size_t)K + scol) : nullptr;

  f32x4 acc[4][4] = {};
  for (int k0 = 0; k0 < K; k0 += 32) {
    bf16x8 a0, a1;
    if (MODE != 0) {
      float4 f0 = *(const float4*)(apf + k0);
      float4 f1 = *(const float4*)(apf + k0 + 4);
      float4 f2 = *(const float4*)(apf + k0 + 8);
      float4 f3 = *(const float4*)(apf + k0 + 12);
      a0 = pack_bf16x8(f0, f1);
      a1 = pack_bf16x8(f2, f3);
    } else {
      a0 = *(const bf16x8*)(aph + k0);
      a1 = *(const bf16x8*)(aph + k0 + 8);
    }
    float4 g0 = *(const float4*)(bp + k0);
    float4 g1 = *(const float4*)(bp + k0 + 4);
    float4 g2 = *(const float4*)(bp + k0 + 8);
    float4 g3 = *(const float4*)(bp + k0 + 12);
    bf16x8 b0 = pack_bf16x8(g0, g1);
    bf16x8 b1 = pack_bf16x8(g2, g3);

    __syncthreads();  // previous iteration's LDS reads done
    *(bf16x8*)&As[srow][scol]     = a0;
    *(bf16x8*)&As[srow][scol + 8] = a1;
    *(bf16x8*)&Bs[srow][scol]     = b0;
    *(bf16x8*)&Bs[srow][scol + 8] = b1;
    __syncthreads();

    bf16x8 af[4], bfr[4];
#pragma unroll
    for (int i = 0; i < 4; ++i) af[i]  = *(const bf16x8*)&As[wr * 64 + i * 16 + lr][lg * 8];
#pragma unroll
    for (int j = 0; j < 4; ++j) bfr[j] = *(const bf16x8*)&Bs[wc * 64 + j * 16 + lr][lg * 8];
#pragma unroll
    for (int i = 0; i < 4; ++i)
#pragma unroll
      for (int j = 0; j < 4; ++j)
        acc[i][j] = __builtin_amdgcn_mfma_f32_16x16x32_bf16(af[i], bfr[j], acc[i][j], 0, 0, 0);
  }
  // epilogue: C/D layout col=lane&15, row=(lane>>4)*4+reg
#pragma unroll
  for (int i = 0; i < 4; ++i)
#pragma unroll
    for (int j = 0; j < 4; ++j) {
      const int row0 = (int)m0 + wr * 64 + i * 16 + lg * 4;
      const int col  = (int)n0 + wc * 64 + j * 16 + lr;
#pragma unroll
      for (int r = 0; r < 4; ++r) {
        const int row = row0 + r;
        if (MODE == 0) {
          ((float*)outv)[(size_t)row * N + col] = acc[i][j][r];
        } else {
          bf16_t* out = (bf16_t*)outv;
          const bf16_t val = (bf16_t)acc[i][j][r];
          const int b = row >> 11, s = row & (S_ - 1);
          const int h = col >> 8,  hd = col & (HD_ - 1);
          if (MODE == 1) out[((size_t)(b * nh + h) * S_ + s) * HD_ + hd] = val;
          else           out[((size_t)(b * NKV_ + h) * HD_ + hd) * S_ + s] = val;
        }
      }
    }
}

// ---------------- fused RMSNorm + RoPE, in place on (B, nh, S, HD) ----------------
__global__ __launch_bounds__(256) void normrope_kernel(bf16_t* __restrict__ x,
                                                       const float* __restrict__ w,
                                                       const float* __restrict__ cosb,
                                                       const float* __restrict__ sinb,
                                                       int nh) {
  const int gid  = blockIdx.x * 4 + (threadIdx.x >> 6);  // row in (b, nh, s)
  const int lane = threadIdx.x & 63;
  const int s  = gid & (S_ - 1);
  const int bh = gid >> 11;          // b*nh + h
  const int b  = bh / nh;
  const int bs = b * S_ + s;

  bf16_t* ptr = x + (size_t)gid * HD_ + lane * 4;
  bf16x4 xv = *(const bf16x4*)ptr;
  float v0 = (float)xv[0], v1 = (float)xv[1], v2 = (float)xv[2], v3 = (float)xv[3];
  float ss = v0 * v0 + v1 * v1 + v2 * v2 + v3 * v3;
#pragma unroll
  for (int off = 1; off < 64; off <<= 1) ss += __shfl_xor(ss, off);
  float r = rsqrtf(ss * (1.0f / HD_) + 1e-6f);

  float4 wv = *(const float4*)(w + lane * 4);
  float x0 = v0 * r * (1.0f + wv.x);
  float x1 = v1 * r * (1.0f + wv.y);
  float x2 = v2 * r * (1.0f + wv.z);
  float x3 = v3 * r * (1.0f + wv.w);

  // rotate_half: dim d pairs with d +/- 128 -> lane ^ 32
  float p0 = __shfl_xor(x0, 32);
  float p1 = __shfl_xor(x1, 32);
  float p2 = __shfl_xor(x2, 32);
  float p3 = __shfl_xor(x3, 32);
  float sgn = (lane < 32) ? -1.0f : 1.0f;

  float4 c  = *(const float4*)(cosb + (size_t)bs * HD_ + lane * 4);
  float4 sn = *(const float4*)(sinb + (size_t)bs * HD_ + lane * 4);
  bf16x4 o;
  o[0] = (bf16_t)(x0 * c.x + sgn * p0 * sn.x);
  o[1] = (bf16_t)(x1 * c.y + sgn * p1 * sn.y);
  o[2] = (bf16_t)(x2 * c.z + sgn * p2 * sn.z);
  o[3] = (bf16_t)(x3 * c.w + sgn * p3 * sn.w);
  *(bf16x4*)ptr = o;
}

// ---------------- attention: 1 wave per 16 q-rows, exact 2-pass softmax ----------------
// qb: (B,NH,S,HD) bf16; kb: (B,NKV,S,HD); vt: (B,NKV,HD,S)
// wout: attn_weights (B,NH,S,S) f32 (upper triangle pre-zeroed); ctx: (B,S,NH*HD) bf16
__global__ __launch_bounds__(64) void attn_kernel(const bf16_t* __restrict__ qb,
                                                  const bf16_t* __restrict__ kb,
                                                  const bf16_t* __restrict__ vt,
                                                  float* __restrict__ wout,
                                                  bf16_t* __restrict__ ctx) {
  __shared__ __align__(16) bf16_t p_lds[16][40];
  const int lane = threadIdx.x;
  const int lr = lane & 15, lg = lane >> 4;
  const int rloc = lg * 4;
  const int q0 = blockIdx.x * 16;
  const int bh = blockIdx.y;
  const int b = bh >> 4, h = bh & 15;
  const int kvh = h >> 1;  // GQA: 2 q-heads per kv-head

  // Q tile (16 x 256) held in registers as 8 A-fragments
  const bf16_t* qptr = qb + ((size_t)(b * NH_ + h) * S_ + q0 + lr) * HD_ + lg * 8;
  bf16x8 qf[8];
#pragma unroll
  for (int c = 0; c < 8; ++c) qf[c] = *(const bf16x8*)(qptr + c * 32);

  const int nkt = (q0 + 16 + 31) >> 5;  // causal: #32-wide k tiles
  const bf16_t* kbase = kb + ((size_t)(b * NKV_ + kvh) * S_ + lr) * HD_ + lg * 8;

  float m[4], l[4];
#pragma unroll
  for (int r = 0; r < 4; ++r) { m[r] = -3.0e38f; l[r] = 0.0f; }

  // ---- pass 1: row max + sum of exp (lane-local online, then 16-lane merge) ----
  for (int kt = 0; kt < nkt; ++kt) {
    const bf16_t* kp = kbase + (size_t)kt * 32 * HD_;
    f32x4 s0 = {0.f, 0.f, 0.f, 0.f}, s1 = {0.f, 0.f, 0.f, 0.f};
#pragma unroll
    for (int c = 0; c < 8; ++c) {
      bf16x8 k0 = *(const bf16x8*)(kp + c * 32);
      bf16x8 k1 = *(const bf16x8*)(kp + 16 * HD_ + c * 32);
      s0 = __builtin_amdgcn_mfma_f32_16x16x32_bf16(qf[c], k0, s0, 0, 0, 0);
      s1 = __builtin_amdgcn_mfma_f32_16x16x32_bf16(qf[c], k1, s1, 0, 0, 0);
    }
    const int col0 = kt * 32 + lr, col1 = col0 + 16;
#pragma unroll
    for (int r = 0; r < 4; ++r) {
      int row = q0 + rloc + r;
      float a  = s0[r] * SCALE_ + (col0 <= row ? 0.0f : NEGBIG);
      float bb = s1[r] * SCALE_ + (col1 <= row ? 0.0f : NEGBIG);
      float mn = fmaxf(m[r], fmaxf(a, bb));
      l[r] = l[r] * __expf(m[r] - mn) + __expf(a - mn) + __expf(bb - mn);
      m[r] = mn;
    }
  }
#pragma unroll
  for (int r = 0; r < 4; ++r) {
#pragma unroll
    for (int off = 1; off < 16; off <<= 1) {
      float mo = __shfl_xor(m[r], off);
      float lo = __shfl_xor(l[r], off);
      float mn = fmaxf(m[r], mo);
      l[r] = l[r] * __expf(m[r] - mn) + lo * __expf(mo - mn);
      m[r] = mn;
    }
  }
  float invl[4];
#pragma unroll
  for (int r = 0; r < 4; ++r) invl[r] = 1.0f / l[r];

  // ---- pass 2: recompute scores, write weights (f32), accumulate PV ----
  f32x4 oacc[16] = {};
  float* wrow = wout + ((size_t)bh * S_ + q0) * S_;
  const bf16_t* vbase = vt + ((size_t)(b * NKV_ + kvh) * HD_ + lr) * S_;

  for (int kt = 0; kt < nkt; ++kt) {
    const bf16_t* kp = kbase + (size_t)kt * 32 * HD_;
    f32x4 s0 = {0.f, 0.f, 0.f, 0.f}, s1 = {0.f, 0.f, 0.f, 0.f};
#pragma unroll
    for (int c = 0; c < 8; ++c) {
      bf16x8 k0 = *(const bf16x8*)(kp + c * 32);
      bf16x8 k1 = *(const bf16x8*)(kp + 16 * HD_ + c * 32);
      s0 = __builtin_amdgcn_mfma_f32_16x16x32_bf16(qf[c], k0, s0, 0, 0, 0);
      s1 = __builtin_amdgcn_mfma_f32_16x16x32_bf16(qf[c], k1, s1, 0, 0, 0);
    }
    const int colb = kt * 32;
    const int col0 = colb + lr, col1 = col0 + 16;
#pragma unroll
    for (int r = 0; r < 4; ++r) {
      int row = q0 + rloc + r;
      float a  = s0[r] * SCALE_ + (col0 <= row ? 0.0f : NEGBIG);
      float bb = s1[r] * SCALE_ + (col1 <= row ? 0.0f : NEGBIG);
      float pa = __expf(a - m[r]);
      float pb = __expf(bb - m[r]);
      wrow[(size_t)(rloc + r) * S_ + col0] = pa * invl[r];
      wrow[(size_t)(rloc + r) * S_ + col1] = pb * invl[r];
      p_lds[rloc + r][lr]      = (bf16_t)pa;
      p_lds[rloc + r][lr + 16] = (bf16_t)pb;
    }
    __syncthreads();
    bf16x8 pf = *(const bf16x8*)&p_lds[lr][lg * 8];  // P as A-fragment
    const bf16_t* vp = vbase + colb + lg * 8;
#pragma unroll
    for (int df = 0; df < 16; ++df) {
      bf16x8 vf = *(const bf16x8*)(vp + (size_t)df * 16 * S_);
      oacc[df] = __builtin_amdgcn_mfma_f32_16x16x32_bf16(pf, vf, oacc[df], 0, 0, 0);
    }
    __syncthreads();
  }
  // epilogue: O / l -> ctx (B, S, NH*HD) bf16
  bf16_t* cp = ctx + ((size_t)b * S_ + q0) * DQ_ + h * HD_;
#pragma unroll
  for (int df = 0; df < 16; ++df)
#pragma unroll
    for (int r = 0; r < 4; ++r)
      cp[(size_t)(rloc + r) * DQ_ + df * 16 + lr] = (bf16_t)(oacc[df][r] * invl[r]);
}

// ---------------- launch ----------------
extern "C" void kernel_launch(void* const* d_in, const int* in_sizes, int n_in,
                              void* d_out, int out_size, void* d_ws, size_t ws_size,
                              hipStream_t stream) {
  const float* hs   = (const float*)d_in[0];
  const float* cosb = (const float*)d_in[1];
  const float* sinb = (const float*)d_in[2];
  // d_in[3] attention_mask: recomputed causally in-kernel (identical 0 / -1e9 values)
  const float* Wq = (const float*)d_in[4];
  const float* Wk = (const float*)d_in[5];
  const float* Wv = (const float*)d_in[6];
  const float* Wo = (const float*)d_in[7];
  const float* qw = (const float*)d_in[8];
  const float* kw = (const float*)d_in[9];

  char* ws = (char*)d_ws;
  // workspace layout (bytes) — 100,663,296 total (96 MB)
  bf16_t* qb  = (bf16_t*)(ws + 0);           // 33,554,432  (B,NH,S,HD)
  bf16_t* kb  = (bf16_t*)(ws + 33554432);    // 16,777,216  (B,NKV,S,HD)
  bf16_t* vt  = (bf16_t*)(ws + 50331648);    // 16,777,216  (B,NKV,HD,S)
  bf16_t* ctx = (bf16_t*)(ws + 67108864);    // 33,554,432  (B,S,NH*HD)

  float* out      = (float*)d_out;                  // f32: reference output dtype
  float* attn_out = out;                            // (B,S,HID) f32
  float* weights  = out + (size_t)B_ * S_ * HID_;   // (B,NH,S,S) f32

  const int M = B_ * S_;  // 4096

  // 1) projections (f32 inputs, bf16 MFMA, fused relayout epilogues)
  gemm_f32w<1><<<dim3(DQ_ / 128, M / 128), 256, 0, stream>>>(hs, Wq, qb, M, DQ_, HID_, NH_);
  gemm_f32w<1><<<dim3(DKV_ / 128, M / 128), 256, 0, stream>>>(hs, Wk, kb, M, DKV_, HID_, NKV_);
  gemm_f32w<2><<<dim3(DKV_ / 128, M / 128), 256, 0, stream>>>(hs, Wv, vt, M, DKV_, HID_, NKV_);

  // 2) norm + rope (in place)
  normrope_kernel<<<(B_ * NH_ * S_) / 4, 256, 0, stream>>>(qb, qw, cosb, sinb, NH_);
  normrope_kernel<<<(B_ * NKV_ * S_) / 4, 256, 0, stream>>>(kb, kw, cosb, sinb, NKV_);

  // 3) attention (zero upper triangle of f32 weights first)
  hipMemsetAsync(weights, 0, (size_t)B_ * NH_ * S_ * S_ * sizeof(float), stream);
  attn_kernel<<<dim3(S_ / 16, B_ * NH_), 64, 0, stream>>>(qb, kb, vt, weights, ctx);

  // 4) output projection -> d_out (f32)
  gemm_f32w<0><<<dim3(HID_ / 128, M / 128), 256, 0, stream>>>(ctx, Wo, attn_out, M, HID_, DQ_, 0);
}

// Round 6
// 1753.596 us; speedup vs baseline: 1.1556x; 1.1556x over previous
//
#include <hip/hip_runtime.h>

// ---------------- problem constants ----------------
#define B_    2
#define S_    2048
#define HID_  3584
#define NH_   16
#define NKV_  8
#define HD_   256
#define DQ_   (NH_ * HD_)    // 4096
#define DKV_  (NKV_ * HD_)   // 2048

static constexpr float SCALE_ = 0.0625f;   // 256^-0.5

typedef __bf16 bf16_t;
typedef __bf16 bf16x8 __attribute__((ext_vector_type(8)));
typedef __bf16 bf16x4 __attribute__((ext_vector_type(4)));
typedef float  f32x4  __attribute__((ext_vector_type(4)));

__device__ inline bf16x8 pack_bf16x8(float4 a, float4 b) {
  bf16x8 r;
  r[0] = (bf16_t)a.x; r[1] = (bf16_t)a.y; r[2] = (bf16_t)a.z; r[3] = (bf16_t)a.w;
  r[4] = (bf16_t)b.x; r[5] = (bf16_t)b.y; r[6] = (bf16_t)b.z; r[7] = (bf16_t)b.w;
  return r;
}

// ---------------- GEMM: C[m][n] = sum_k A[m][k] * Bt[n][k] ---------------- (unchanged, passing)
// MODE 0: A = bf16, OUT = f32, plain row-major [M][N]       (o-proj -> d_out)
// MODE 1: A = f32,  OUT = bf16, relayout to (B, nh, S, HD)  (Q, K projections)
// MODE 2: A = f32,  OUT = bf16, transpose to (B, NKV, HD, S) (V projection)
template<int MODE>
__global__ __launch_bounds__(256) void gemm_f32w(const void* __restrict__ Av,
                                                 const float* __restrict__ Bt,
                                                 void* __restrict__ outv,
                                                 int M, int N, int K, int nh) {
  __shared__ __align__(16) bf16_t As[128][40];
  __shared__ __align__(16) bf16_t Bs[128][40];
  const int t = threadIdx.x;
  const int lane = t & 63, wave = t >> 6;
  const int wr = wave >> 1, wc = wave & 1;
  const int lr = lane & 15, lg = lane >> 4;
  const size_t m0 = (size_t)blockIdx.y * 128, n0 = (size_t)blockIdx.x * 128;
  const int srow = t >> 1, scol = (t & 1) * 16;

  const float*  bp  = Bt + (n0 + srow) * (size_t)K + scol;
  const float*  apf = (MODE != 0) ? ((const float*)Av + (m0 + srow) * (size_t)K + scol) : nullptr;
  const bf16_t* aph = (MODE == 0) ? ((const bf16_t*)Av + (m0 + srow) * (size_t)K + scol) : nullptr;

  f32x4 acc[4][4] = {};
  for (int k0 = 0; k0 < K; k0 += 32) {
    bf16x8 a0, a1;
    if (MODE != 0) {
      float4 f0 = *(const float4*)(apf + k0);
      float4 f1 = *(const float4*)(apf + k0 + 4);
      float4 f2 = *(const float4*)(apf + k0 + 8);
      float4 f3 = *(const float4*)(apf + k0 + 12);
      a0 = pack_bf16x8(f0, f1);
      a1 = pack_bf16x8(f2, f3);
    } else {
      a0 = *(const bf16x8*)(aph + k0);
      a1 = *(const bf16x8*)(aph + k0 + 8);
    }
    float4 g0 = *(const float4*)(bp + k0);
    float4 g1 = *(const float4*)(bp + k0 + 4);
    float4 g2 = *(const float4*)(bp + k0 + 8);
    float4 g3 = *(const float4*)(bp + k0 + 12);
    bf16x8 b0 = pack_bf16x8(g0, g1);
    bf16x8 b1 = pack_bf16x8(g2, g3);

    __syncthreads();
    *(bf16x8*)&As[srow][scol]     = a0;
    *(bf16x8*)&As[srow][scol + 8] = a1;
    *(bf16x8*)&Bs[srow][scol]     = b0;
    *(bf16x8*)&Bs[srow][scol + 8] = b1;
    __syncthreads();

    bf16x8 af[4], bfr[4];
#pragma unroll
    for (int i = 0; i < 4; ++i) af[i]  = *(const bf16x8*)&As[wr * 64 + i * 16 + lr][lg * 8];
#pragma unroll
    for (int j = 0; j < 4; ++j) bfr[j] = *(const bf16x8*)&Bs[wc * 64 + j * 16 + lr][lg * 8];
#pragma unroll
    for (int i = 0; i < 4; ++i)
#pragma unroll
      for (int j = 0; j < 4; ++j)
        acc[i][j] = __builtin_amdgcn_mfma_f32_16x16x32_bf16(af[i], bfr[j], acc[i][j], 0, 0, 0);
  }
#pragma unroll
  for (int i = 0; i < 4; ++i)
#pragma unroll
    for (int j = 0; j < 4; ++j) {
      const int row0 = (int)m0 + wr * 64 + i * 16 + lg * 4;
      const int col  = (int)n0 + wc * 64 + j * 16 + lr;
#pragma unroll
      for (int r = 0; r < 4; ++r) {
        const int row = row0 + r;
        if (MODE == 0) {
          ((float*)outv)[(size_t)row * N + col] = acc[i][j][r];
        } else {
          bf16_t* out = (bf16_t*)outv;
          const bf16_t val = (bf16_t)acc[i][j][r];
          const int b = row >> 11, s = row & (S_ - 1);
          const int h = col >> 8,  hd = col & (HD_ - 1);
          if (MODE == 1) out[((size_t)(b * nh + h) * S_ + s) * HD_ + hd] = val;
          else           out[((size_t)(b * NKV_ + h) * HD_ + hd) * S_ + s] = val;
        }
      }
    }
}

// ---------------- fused RMSNorm + RoPE (in place) + optional max|k|^2 via atomicMax ----------------
__global__ __launch_bounds__(256) void normrope_kernel(bf16_t* __restrict__ x,
                                                       const float* __restrict__ w,
                                                       const float* __restrict__ cosb,
                                                       const float* __restrict__ sinb,
                                                       int nh, unsigned* __restrict__ kmaxbuf) {
  const int gid  = blockIdx.x * 4 + (threadIdx.x >> 6);  // row in (b, nh, s)
  const int lane = threadIdx.x & 63;
  const int s  = gid & (S_ - 1);
  const int bh = gid >> 11;          // b*nh + h
  const int b  = bh / nh;
  const int bs = b * S_ + s;

  bf16_t* ptr = x + (size_t)gid * HD_ + lane * 4;
  bf16x4 xv = *(const bf16x4*)ptr;
  float v0 = (float)xv[0], v1 = (float)xv[1], v2 = (float)xv[2], v3 = (float)xv[3];
  float ss = v0 * v0 + v1 * v1 + v2 * v2 + v3 * v3;
#pragma unroll
  for (int off = 1; off < 64; off <<= 1) ss += __shfl_xor(ss, off);
  float r = rsqrtf(ss * (1.0f / HD_) + 1e-6f);

  float4 wv = *(const float4*)(w + lane * 4);
  float x0 = v0 * r * (1.0f + wv.x);
  float x1 = v1 * r * (1.0f + wv.y);
  float x2 = v2 * r * (1.0f + wv.z);
  float x3 = v3 * r * (1.0f + wv.w);

  if (kmaxbuf != nullptr) {   // row norm^2 (RoPE is a rotation per pair: norm preserved)
    float s2 = x0 * x0 + x1 * x1 + x2 * x2 + x3 * x3;
#pragma unroll
    for (int off = 1; off < 64; off <<= 1) s2 += __shfl_xor(s2, off);
    if (lane == 0) atomicMax(&kmaxbuf[bh], __float_as_uint(s2));  // nh==NKV here -> idx = bh
  }

  // rotate_half: dim d pairs with d +/- 128 -> lane ^ 32
  float p0 = __shfl_xor(x0, 32);
  float p1 = __shfl_xor(x1, 32);
  float p2 = __shfl_xor(x2, 32);
  float p3 = __shfl_xor(x3, 32);
  float sgn = (lane < 32) ? -1.0f : 1.0f;

  float4 c  = *(const float4*)(cosb + (size_t)bs * HD_ + lane * 4);
  float4 sn = *(const float4*)(sinb + (size_t)bs * HD_ + lane * 4);
  bf16x4 o;
  o[0] = (bf16_t)(x0 * c.x + sgn * p0 * sn.x);
  o[1] = (bf16_t)(x1 * c.y + sgn * p1 * sn.y);
  o[2] = (bf16_t)(x2 * c.z + sgn * p2 * sn.z);
  o[3] = (bf16_t)(x3 * c.w + sgn * p3 * sn.w);
  *(bf16x4*)ptr = o;
}

// ---------------- single-pass flash attention, 4 waves x 16 q-rows, bound-based softmax ----------------
// qb: (B,NH,S,HD); kb: (B,NKV,S,HD); vt: (B,NKV,HD,S)
// wout: f32 unnormalized p-tilde (lower triangle); linv: 1/l per row; ctx: (B,S,NH*HD) bf16
__global__ __launch_bounds__(256) void attn1p_kernel(const bf16_t* __restrict__ qb,
                                                     const bf16_t* __restrict__ kb,
                                                     const bf16_t* __restrict__ vt,
                                                     const unsigned* __restrict__ kmaxbuf,
                                                     float* __restrict__ wout,
                                                     float* __restrict__ linv,
                                                     bf16_t* __restrict__ ctx) {
  __shared__ __align__(16) bf16_t Ks[32][264];      // +8 pad
  __shared__ __align__(16) bf16_t Vs[256][40];      // d-major, +8 pad
  __shared__ __align__(16) bf16_t p_lds[4][16][40];
  __shared__ float qn_lds[4][16];

  const int t = threadIdx.x, w = t >> 6, lane = t & 63;
  const int lr = lane & 15, lg = lane >> 4, rloc = lg * 4;
  const int q0b = blockIdx.x * 64;
  const int q0  = q0b + w * 16;                 // this wave's q-row base
  const int bh = blockIdx.y, b = bh >> 4, h = bh & 15, kvh = h >> 1;

  // Q tile (16 x 256) as 8 A-fragments
  const bf16_t* qptr = qb + ((size_t)(b * NH_ + h) * S_ + q0 + lr) * HD_ + lg * 8;
  bf16x8 qf[8];
#pragma unroll
  for (int c = 0; c < 8; ++c) qf[c] = *(const bf16x8*)(qptr + c * 32);

  // |q_row|^2 for row lr -> transpose to accumulator-row order via LDS
  float qn = 0.0f;
#pragma unroll
  for (int c = 0; c < 8; ++c)
#pragma unroll
    for (int e = 0; e < 8; ++e) { float v = (float)qf[c][e]; qn += v * v; }
  qn += __shfl_xor(qn, 16);
  qn += __shfl_xor(qn, 32);
  if (lg == 0) qn_lds[w][lr] = qn;
  __syncthreads();
  const float kmax2 = __uint_as_float(kmaxbuf[b * NKV_ + kvh]);
  float mb[4];
#pragma unroll
  for (int r = 0; r < 4; ++r)
    mb[r] = SCALE_ * sqrtf(qn_lds[w][rloc + r] * kmax2) + 1.0f;  // >= any score, with margin

  float l[4] = {0.f, 0.f, 0.f, 0.f};
  f32x4 oacc[16] = {};
  const int nkt = (q0b + 64) >> 5;
  float* wrow = wout + ((size_t)bh * S_ + q0) * S_;
  const bf16_t* kgb = kb + (size_t)(b * NKV_ + kvh) * S_ * HD_;
  const bf16_t* vgb = vt + (size_t)(b * NKV_ + kvh) * HD_ * S_;

  const int s_st = t >> 3, c_st = (t & 7) * 32;   // K staging: row s_st, 32 cols
  const int vd   = t >> 3, vc   = (t & 7) * 4;    // V staging: rows vd+32i, 4 cols

  for (int kt = 0; kt < nkt; ++kt) {
    const int colb = kt * 32;
    __syncthreads();   // previous tile's LDS reads complete
    {  // stage K tile (32 x 256) coalesced
      const bf16_t* src = kgb + (size_t)(colb + s_st) * HD_ + c_st;
      bf16x8 k0 = *(const bf16x8*)(src);
      bf16x8 k1 = *(const bf16x8*)(src + 8);
      bf16x8 k2 = *(const bf16x8*)(src + 16);
      bf16x8 k3 = *(const bf16x8*)(src + 24);
      *(bf16x8*)&Ks[s_st][c_st]      = k0;
      *(bf16x8*)&Ks[s_st][c_st + 8]  = k1;
      *(bf16x8*)&Ks[s_st][c_st + 16] = k2;
      *(bf16x8*)&Ks[s_st][c_st + 24] = k3;
    }
#pragma unroll
    for (int i = 0; i < 8; ++i) {  // stage V tile (256 d x 32 s) from vt
      const int d = vd + i * 32;
      bf16x4 vv = *(const bf16x4*)(vgb + (size_t)d * S_ + colb + vc);
      *(bf16x4*)&Vs[d][vc] = vv;
    }
    __syncthreads();

    if (colb <= q0 + 15) {   // wave active for this tile
      f32x4 s0 = {0.f, 0.f, 0.f, 0.f}, s1 = {0.f, 0.f, 0.f, 0.f};
#pragma unroll
      for (int c = 0; c < 8; ++c) {
        bf16x8 k0 = *(const bf16x8*)&Ks[lr][c * 32 + lg * 8];
        bf16x8 k1 = *(const bf16x8*)&Ks[16 + lr][c * 32 + lg * 8];
        s0 = __builtin_amdgcn_mfma_f32_16x16x32_bf16(qf[c], k0, s0, 0, 0, 0);
        s1 = __builtin_amdgcn_mfma_f32_16x16x32_bf16(qf[c], k1, s1, 0, 0, 0);
      }
      const int col0 = colb + lr, col1 = col0 + 16;
#pragma unroll
      for (int r = 0; r < 4; ++r) {
        const int row = q0 + rloc + r;
        const float pa = (col0 <= row) ? __expf(s0[r] * SCALE_ - mb[r]) : 0.0f;
        const float pb = (col1 <= row) ? __expf(s1[r] * SCALE_ - mb[r]) : 0.0f;
        l[r] += pa + pb;
        wrow[(size_t)(rloc + r) * S_ + col0] = pa;
        wrow[(size_t)(rloc + r) * S_ + col1] = pb;
        p_lds[w][rloc + r][lr]      = (bf16_t)pa;
        p_lds[w][rloc + r][lr + 16] = (bf16_t)pb;
      }
      bf16x8 pf = *(const bf16x8*)&p_lds[w][lr][lg * 8];   // P as A-fragment
#pragma unroll
      for (int df = 0; df < 16; ++df) {
        bf16x8 vf = *(const bf16x8*)&Vs[df * 16 + lr][lg * 8];
        oacc[df] = __builtin_amdgcn_mfma_f32_16x16x32_bf16(pf, vf, oacc[df], 0, 0, 0);
      }
    }
  }
  // row sum l: reduce across lr lanes (same lg)
#pragma unroll
  for (int r = 0; r < 4; ++r) {
    l[r] += __shfl_xor(l[r], 1);
    l[r] += __shfl_xor(l[r], 2);
    l[r] += __shfl_xor(l[r], 4);
    l[r] += __shfl_xor(l[r], 8);
  }
  float invl[4];
#pragma unroll
  for (int r = 0; r < 4; ++r) invl[r] = 1.0f / l[r];

  bf16_t* cp = ctx + ((size_t)b * S_ + q0) * DQ_ + h * HD_;
#pragma unroll
  for (int df = 0; df < 16; ++df)
#pragma unroll
    for (int r = 0; r < 4; ++r)
      cp[(size_t)(rloc + r) * DQ_ + df * 16 + lr] = (bf16_t)(oacc[df][r] * invl[r]);

  if (lr == 0) {
#pragma unroll
    for (int r = 0; r < 4; ++r) linv[(size_t)bh * S_ + q0 + rloc + r] = invl[r];
  }
}

// ---------------- weights post-pass: scale lower triangle by 1/l, zero upper ----------------
__global__ __launch_bounds__(256) void wscale_kernel(float* __restrict__ wbuf,
                                                     const float* __restrict__ linv) {
  const int wv = threadIdx.x >> 6, lane = threadIdx.x & 63;
  const size_t rg = (size_t)blockIdx.x * 4 + wv;     // global row in (B*NH, S)
  const int row = (int)(rg & (S_ - 1));
  const float inv = linv[rg];
  float* base = wbuf + rg * S_;
#pragma unroll
  for (int i = 0; i < 8; ++i) {
    const int c0 = (i * 64 + lane) * 4;
    float4 v;
    if (c0 > row) {
      v = make_float4(0.f, 0.f, 0.f, 0.f);
    } else {
      v = *(const float4*)(base + c0);
      v.x = (c0 + 0 <= row) ? v.x * inv : 0.f;
      v.y = (c0 + 1 <= row) ? v.y * inv : 0.f;
      v.z = (c0 + 2 <= row) ? v.z * inv : 0.f;
      v.w = (c0 + 3 <= row) ? v.w * inv : 0.f;
    }
    *(float4*)(base + c0) = v;
  }
}

// ---------------- launch ----------------
extern "C" void kernel_launch(void* const* d_in, const int* in_sizes, int n_in,
                              void* d_out, int out_size, void* d_ws, size_t ws_size,
                              hipStream_t stream) {
  const float* hs   = (const float*)d_in[0];
  const float* cosb = (const float*)d_in[1];
  const float* sinb = (const float*)d_in[2];
  // d_in[3] attention_mask: recomputed causally in-kernel
  const float* Wq = (const float*)d_in[4];
  const float* Wk = (const float*)d_in[5];
  const float* Wv = (const float*)d_in[6];
  const float* Wo = (const float*)d_in[7];
  const float* qw = (const float*)d_in[8];
  const float* kw = (const float*)d_in[9];

  char* ws = (char*)d_ws;
  bf16_t* qb   = (bf16_t*)(ws + 0);            // 33,554,432  (B,NH,S,HD)
  bf16_t* kb   = (bf16_t*)(ws + 33554432);     // 16,777,216  (B,NKV,S,HD)
  bf16_t* vt   = (bf16_t*)(ws + 50331648);     // 16,777,216  (B,NKV,HD,S)
  bf16_t* ctx  = (bf16_t*)(ws + 67108864);     // 33,554,432  (B,S,NH*HD)
  float*  linv = (float*)(ws + 100663296);     //    262,144  (B*NH*S)
  unsigned* km = (unsigned*)(ws + 100925440);  //         64  (B*NKV)

  float* out      = (float*)d_out;
  float* attn_out = out;                            // (B,S,HID) f32
  float* weights  = out + (size_t)B_ * S_ * HID_;   // (B,NH,S,S) f32

  const int M = B_ * S_;  // 4096

  // 1) projections
  gemm_f32w<1><<<dim3(DQ_ / 128, M / 128), 256, 0, stream>>>(hs, Wq, qb, M, DQ_, HID_, NH_);
  gemm_f32w<1><<<dim3(DKV_ / 128, M / 128), 256, 0, stream>>>(hs, Wk, kb, M, DKV_, HID_, NKV_);
  gemm_f32w<2><<<dim3(DKV_ / 128, M / 128), 256, 0, stream>>>(hs, Wv, vt, M, DKV_, HID_, NKV_);

  // 2) norm + rope (in place); K pass also produces max|k|^2 per (b,kv-head)
  hipMemsetAsync(km, 0, B_ * NKV_ * sizeof(unsigned), stream);
  normrope_kernel<<<(B_ * NH_ * S_) / 4, 256, 0, stream>>>(qb, qw, cosb, sinb, NH_, nullptr);
  normrope_kernel<<<(B_ * NKV_ * S_) / 4, 256, 0, stream>>>(kb, kw, cosb, sinb, NKV_, km);

  // 3) single-pass attention (unnormalized p-tilde into weights buffer)
  attn1p_kernel<<<dim3(S_ / 64, B_ * NH_), 256, 0, stream>>>(qb, kb, vt, km, weights, linv, ctx);

  // 4) weights normalization + upper-triangle zeros
  wscale_kernel<<<(B_ * NH_ * S_) / 4, 256, 0, stream>>>(weights, linv);

  // 5) output projection -> d_out (f32)
  gemm_f32w<0><<<dim3(HID_ / 128, M / 128), 256, 0, stream>>>(ctx, Wo, attn_out, M, HID_, DQ_, 0);
}

// Round 7
// 1391.627 us; speedup vs baseline: 1.4562x; 1.2601x over previous
//
#include <hip/hip_runtime.h>

// ---------------- problem constants ----------------
#define B_    2
#define S_    2048
#define HID_  3584
#define NH_   16
#define NKV_  8
#define HD_   256
#define DQ_   (NH_ * HD_)    // 4096
#define DKV_  (NKV_ * HD_)   // 2048

static constexpr float SCALE_ = 0.0625f;   // 256^-0.5

typedef __bf16 bf16_t;
typedef __bf16 bf16x8 __attribute__((ext_vector_type(8)));
typedef __bf16 bf16x4 __attribute__((ext_vector_type(4)));
typedef float  f32x4  __attribute__((ext_vector_type(4)));

__device__ inline bf16x8 pack_bf16x8(float4 a, float4 b) {
  bf16x8 r;
  r[0] = (bf16_t)a.x; r[1] = (bf16_t)a.y; r[2] = (bf16_t)a.z; r[3] = (bf16_t)a.w;
  r[4] = (bf16_t)b.x; r[5] = (bf16_t)b.y; r[6] = (bf16_t)b.z; r[7] = (bf16_t)b.w;
  return r;
}

// ---------------- GEMM: C[m][n] = sum_k A[m][k] * Bt[n][k] ---------------- (unchanged, passing)
// MODE 0: A = bf16, OUT = f32, plain row-major [M][N]       (o-proj -> d_out)
// MODE 1: A = f32,  OUT = bf16, relayout to (B, nh, S, HD)  (Q, K projections)
// MODE 2: A = f32,  OUT = bf16, transpose to (B, NKV, HD, S) (V projection)
template<int MODE>
__global__ __launch_bounds__(256) void gemm_f32w(const void* __restrict__ Av,
                                                 const float* __restrict__ Bt,
                                                 void* __restrict__ outv,
                                                 int M, int N, int K, int nh) {
  __shared__ __align__(16) bf16_t As[128][40];
  __shared__ __align__(16) bf16_t Bs[128][40];
  const int t = threadIdx.x;
  const int lane = t & 63, wave = t >> 6;
  const int wr = wave >> 1, wc = wave & 1;
  const int lr = lane & 15, lg = lane >> 4;
  const size_t m0 = (size_t)blockIdx.y * 128, n0 = (size_t)blockIdx.x * 128;
  const int srow = t >> 1, scol = (t & 1) * 16;

  const float*  bp  = Bt + (n0 + srow) * (size_t)K + scol;
  const float*  apf = (MODE != 0) ? ((const float*)Av + (m0 + srow) * (size_t)K + scol) : nullptr;
  const bf16_t* aph = (MODE == 0) ? ((const bf16_t*)Av + (m0 + srow) * (size_t)K + scol) : nullptr;

  f32x4 acc[4][4] = {};
  for (int k0 = 0; k0 < K; k0 += 32) {
    bf16x8 a0, a1;
    if (MODE != 0) {
      float4 f0 = *(const float4*)(apf + k0);
      float4 f1 = *(const float4*)(apf + k0 + 4);
      float4 f2 = *(const float4*)(apf + k0 + 8);
      float4 f3 = *(const float4*)(apf + k0 + 12);
      a0 = pack_bf16x8(f0, f1);
      a1 = pack_bf16x8(f2, f3);
    } else {
      a0 = *(const bf16x8*)(aph + k0);
      a1 = *(const bf16x8*)(aph + k0 + 8);
    }
    float4 g0 = *(const float4*)(bp + k0);
    float4 g1 = *(const float4*)(bp + k0 + 4);
    float4 g2 = *(const float4*)(bp + k0 + 8);
    float4 g3 = *(const float4*)(bp + k0 + 12);
    bf16x8 b0 = pack_bf16x8(g0, g1);
    bf16x8 b1 = pack_bf16x8(g2, g3);

    __syncthreads();
    *(bf16x8*)&As[srow][scol]     = a0;
    *(bf16x8*)&As[srow][scol + 8] = a1;
    *(bf16x8*)&Bs[srow][scol]     = b0;
    *(bf16x8*)&Bs[srow][scol + 8] = b1;
    __syncthreads();

    bf16x8 af[4], bfr[4];
#pragma unroll
    for (int i = 0; i < 4; ++i) af[i]  = *(const bf16x8*)&As[wr * 64 + i * 16 + lr][lg * 8];
#pragma unroll
    for (int j = 0; j < 4; ++j) bfr[j] = *(const bf16x8*)&Bs[wc * 64 + j * 16 + lr][lg * 8];
#pragma unroll
    for (int i = 0; i < 4; ++i)
#pragma unroll
      for (int j = 0; j < 4; ++j)
        acc[i][j] = __builtin_amdgcn_mfma_f32_16x16x32_bf16(af[i], bfr[j], acc[i][j], 0, 0, 0);
  }
#pragma unroll
  for (int i = 0; i < 4; ++i)
#pragma unroll
    for (int j = 0; j < 4; ++j) {
      const int row0 = (int)m0 + wr * 64 + i * 16 + lg * 4;
      const int col  = (int)n0 + wc * 64 + j * 16 + lr;
#pragma unroll
      for (int r = 0; r < 4; ++r) {
        const int row = row0 + r;
        if (MODE == 0) {
          ((float*)outv)[(size_t)row * N + col] = acc[i][j][r];
        } else {
          bf16_t* out = (bf16_t*)outv;
          const bf16_t val = (bf16_t)acc[i][j][r];
          const int b = row >> 11, s = row & (S_ - 1);
          const int h = col >> 8,  hd = col & (HD_ - 1);
          if (MODE == 1) out[((size_t)(b * nh + h) * S_ + s) * HD_ + hd] = val;
          else           out[((size_t)(b * NKV_ + h) * HD_ + hd) * S_ + s] = val;
        }
      }
    }
}

// ---------------- fused RMSNorm + RoPE (in place), (b, s, h) block order ----------------
// optional knorm: per-row |x|^2 after norm (plain store, no atomics)
template<int LOGNH>
__global__ __launch_bounds__(256) void normrope_kernel(bf16_t* __restrict__ x,
                                                       const float* __restrict__ w,
                                                       const float* __restrict__ cosb,
                                                       const float* __restrict__ sinb,
                                                       float* __restrict__ knorm) {
  const int gid  = blockIdx.x * 4 + (threadIdx.x >> 6);  // (b, s, h) order: h innermost
  const int lane = threadIdx.x & 63;
  const int nh = 1 << LOGNH;
  const int h  = gid & (nh - 1);
  const int bs = gid >> LOGNH;                 // b*S + s
  const int b  = bs >> 11, s = bs & (S_ - 1);
  const int rowi = (b * nh + h) * S_ + s;      // row in x's (B, nh, S) layout

  bf16_t* ptr = x + (size_t)rowi * HD_ + lane * 4;
  bf16x4 xv = *(const bf16x4*)ptr;
  float v0 = (float)xv[0], v1 = (float)xv[1], v2 = (float)xv[2], v3 = (float)xv[3];
  float ss = v0 * v0 + v1 * v1 + v2 * v2 + v3 * v3;
#pragma unroll
  for (int off = 1; off < 64; off <<= 1) ss += __shfl_xor(ss, off);
  float r = rsqrtf(ss * (1.0f / HD_) + 1e-6f);

  float4 wv = *(const float4*)(w + lane * 4);
  float x0 = v0 * r * (1.0f + wv.x);
  float x1 = v1 * r * (1.0f + wv.y);
  float x2 = v2 * r * (1.0f + wv.z);
  float x3 = v3 * r * (1.0f + wv.w);

  if (knorm != nullptr) {   // row norm^2 (RoPE rotates pairs: norm preserved)
    float s2 = x0 * x0 + x1 * x1 + x2 * x2 + x3 * x3;
#pragma unroll
    for (int off = 1; off < 64; off <<= 1) s2 += __shfl_xor(s2, off);
    if (lane == 0) knorm[rowi] = s2;
  }

  // rotate_half: dim d pairs with d +/- 128 -> lane ^ 32
  float p0 = __shfl_xor(x0, 32);
  float p1 = __shfl_xor(x1, 32);
  float p2 = __shfl_xor(x2, 32);
  float p3 = __shfl_xor(x3, 32);
  float sgn = (lane < 32) ? -1.0f : 1.0f;

  float4 c  = *(const float4*)(cosb + (size_t)bs * HD_ + lane * 4);
  float4 sn = *(const float4*)(sinb + (size_t)bs * HD_ + lane * 4);
  bf16x4 o;
  o[0] = (bf16_t)(x0 * c.x + sgn * p0 * sn.x);
  o[1] = (bf16_t)(x1 * c.y + sgn * p1 * sn.y);
  o[2] = (bf16_t)(x2 * c.z + sgn * p2 * sn.z);
  o[3] = (bf16_t)(x3 * c.w + sgn * p3 * sn.w);
  *(bf16x4*)ptr = o;
}

// ---------------- per-(b,kv-head) max of knorm (no atomics) ----------------
__global__ __launch_bounds__(256) void kmax_reduce_kernel(const float* __restrict__ knorm,
                                                          float* __restrict__ km) {
  __shared__ float red[4];
  const int t = threadIdx.x;
  const float* src = knorm + (size_t)blockIdx.x * S_;
  float m = 0.0f;
  for (int i = t; i < S_; i += 256) m = fmaxf(m, src[i]);
#pragma unroll
  for (int off = 1; off < 64; off <<= 1) m = fmaxf(m, __shfl_xor(m, off));
  if ((t & 63) == 0) red[t >> 6] = m;
  __syncthreads();
  if (t == 0) km[blockIdx.x] = fmaxf(fmaxf(red[0], red[1]), fmaxf(red[2], red[3]));
}

// ---------------- single-pass flash attention, 4 waves x 16 q-rows, bound-based softmax ----------------
__global__ __launch_bounds__(256) void attn1p_kernel(const bf16_t* __restrict__ qb,
                                                     const bf16_t* __restrict__ kb,
                                                     const bf16_t* __restrict__ vt,
                                                     const float* __restrict__ kmaxbuf,
                                                     float* __restrict__ wout,
                                                     float* __restrict__ linv,
                                                     bf16_t* __restrict__ ctx) {
  __shared__ __align__(16) bf16_t Ks[32][264];      // +8 pad
  __shared__ __align__(16) bf16_t Vs[256][40];      // d-major, +8 pad
  __shared__ __align__(16) bf16_t p_lds[4][16][40];
  __shared__ float qn_lds[4][16];

  const int t = threadIdx.x, w = t >> 6, lane = t & 63;
  const int lr = lane & 15, lg = lane >> 4, rloc = lg * 4;
  const int q0b = blockIdx.x * 64;
  const int q0  = q0b + w * 16;                 // this wave's q-row base
  const int bh = blockIdx.y, b = bh >> 4, h = bh & 15, kvh = h >> 1;

  // Q tile (16 x 256) as 8 A-fragments
  const bf16_t* qptr = qb + ((size_t)(b * NH_ + h) * S_ + q0 + lr) * HD_ + lg * 8;
  bf16x8 qf[8];
#pragma unroll
  for (int c = 0; c < 8; ++c) qf[c] = *(const bf16x8*)(qptr + c * 32);

  // |q_row|^2 for row lr -> transpose to accumulator-row order via LDS
  float qn = 0.0f;
#pragma unroll
  for (int c = 0; c < 8; ++c)
#pragma unroll
    for (int e = 0; e < 8; ++e) { float v = (float)qf[c][e]; qn += v * v; }
  qn += __shfl_xor(qn, 16);
  qn += __shfl_xor(qn, 32);
  if (lg == 0) qn_lds[w][lr] = qn;
  __syncthreads();
  const float kmax2 = kmaxbuf[b * NKV_ + kvh];
  float mb[4];
#pragma unroll
  for (int r = 0; r < 4; ++r)
    mb[r] = SCALE_ * sqrtf(qn_lds[w][rloc + r] * kmax2) + 1.0f;  // >= any score, with margin

  float l[4] = {0.f, 0.f, 0.f, 0.f};
  f32x4 oacc[16] = {};
  const int nkt = (q0b + 64) >> 5;
  float* wrow = wout + ((size_t)bh * S_ + q0) * S_;
  const bf16_t* kgb = kb + (size_t)(b * NKV_ + kvh) * S_ * HD_;
  const bf16_t* vgb = vt + (size_t)(b * NKV_ + kvh) * HD_ * S_;

  const int s_st = t >> 3, c_st = (t & 7) * 32;   // K staging: row s_st, 32 cols
  const int vd   = t >> 3, vc   = (t & 7) * 4;    // V staging: rows vd+32i, 4 cols

  for (int kt = 0; kt < nkt; ++kt) {
    const int colb = kt * 32;
    __syncthreads();   // previous tile's LDS reads complete
    {  // stage K tile (32 x 256) coalesced
      const bf16_t* src = kgb + (size_t)(colb + s_st) * HD_ + c_st;
      bf16x8 k0 = *(const bf16x8*)(src);
      bf16x8 k1 = *(const bf16x8*)(src + 8);
      bf16x8 k2 = *(const bf16x8*)(src + 16);
      bf16x8 k3 = *(const bf16x8*)(src + 24);
      *(bf16x8*)&Ks[s_st][c_st]      = k0;
      *(bf16x8*)&Ks[s_st][c_st + 8]  = k1;
      *(bf16x8*)&Ks[s_st][c_st + 16] = k2;
      *(bf16x8*)&Ks[s_st][c_st + 24] = k3;
    }
#pragma unroll
    for (int i = 0; i < 8; ++i) {  // stage V tile (256 d x 32 s) from vt
      const int d = vd + i * 32;
      bf16x4 vv = *(const bf16x4*)(vgb + (size_t)d * S_ + colb + vc);
      *(bf16x4*)&Vs[d][vc] = vv;
    }
    __syncthreads();

    if (colb <= q0 + 15) {   // wave active for this tile
      f32x4 s0 = {0.f, 0.f, 0.f, 0.f}, s1 = {0.f, 0.f, 0.f, 0.f};
#pragma unroll
      for (int c = 0; c < 8; ++c) {
        bf16x8 k0 = *(const bf16x8*)&Ks[lr][c * 32 + lg * 8];
        bf16x8 k1 = *(const bf16x8*)&Ks[16 + lr][c * 32 + lg * 8];
        s0 = __builtin_amdgcn_mfma_f32_16x16x32_bf16(qf[c], k0, s0, 0, 0, 0);
        s1 = __builtin_amdgcn_mfma_f32_16x16x32_bf16(qf[c], k1, s1, 0, 0, 0);
      }
      const int col0 = colb + lr, col1 = col0 + 16;
#pragma unroll
      for (int r = 0; r < 4; ++r) {
        const int row = q0 + rloc + r;
        const float pa = (col0 <= row) ? __expf(s0[r] * SCALE_ - mb[r]) : 0.0f;
        const float pb = (col1 <= row) ? __expf(s1[r] * SCALE_ - mb[r]) : 0.0f;
        l[r] += pa + pb;
        wrow[(size_t)(rloc + r) * S_ + col0] = pa;
        wrow[(size_t)(rloc + r) * S_ + col1] = pb;
        p_lds[w][rloc + r][lr]      = (bf16_t)pa;
        p_lds[w][rloc + r][lr + 16] = (bf16_t)pb;
      }
      bf16x8 pf = *(const bf16x8*)&p_lds[w][lr][lg * 8];   // P as A-fragment
#pragma unroll
      for (int df = 0; df < 16; ++df) {
        bf16x8 vf = *(const bf16x8*)&Vs[df * 16 + lr][lg * 8];
        oacc[df] = __builtin_amdgcn_mfma_f32_16x16x32_bf16(pf, vf, oacc[df], 0, 0, 0);
      }
    }
  }
  // row sum l: reduce across lr lanes (same lg)
#pragma unroll
  for (int r = 0; r < 4; ++r) {
    l[r] += __shfl_xor(l[r], 1);
    l[r] += __shfl_xor(l[r], 2);
    l[r] += __shfl_xor(l[r], 4);
    l[r] += __shfl_xor(l[r], 8);
  }
  float invl[4];
#pragma unroll
  for (int r = 0; r < 4; ++r) invl[r] = 1.0f / l[r];

  bf16_t* cp = ctx + ((size_t)b * S_ + q0) * DQ_ + h * HD_;
#pragma unroll
  for (int df = 0; df < 16; ++df)
#pragma unroll
    for (int r = 0; r < 4; ++r)
      cp[(size_t)(rloc + r) * DQ_ + df * 16 + lr] = (bf16_t)(oacc[df][r] * invl[r]);

  if (lr == 0) {
#pragma unroll
    for (int r = 0; r < 4; ++r) linv[(size_t)bh * S_ + q0 + rloc + r] = invl[r];
  }
}

// ---------------- weights post-pass: scale lower triangle by 1/l, zero upper ----------------
__global__ __launch_bounds__(256) void wscale_kernel(float* __restrict__ wbuf,
                                                     const float* __restrict__ linv) {
  const int wv = threadIdx.x >> 6, lane = threadIdx.x & 63;
  const size_t rg = (size_t)blockIdx.x * 4 + wv;     // global row in (B*NH, S)
  const int row = (int)(rg & (S_ - 1));
  const float inv = linv[rg];
  float* base = wbuf + rg * S_;
#pragma unroll
  for (int i = 0; i < 8; ++i) {
    const int c0 = (i * 64 + lane) * 4;
    float4 v;
    if (c0 > row) {
      v = make_float4(0.f, 0.f, 0.f, 0.f);
    } else {
      v = *(const float4*)(base + c0);
      v.x = (c0 + 0 <= row) ? v.x * inv : 0.f;
      v.y = (c0 + 1 <= row) ? v.y * inv : 0.f;
      v.z = (c0 + 2 <= row) ? v.z * inv : 0.f;
      v.w = (c0 + 3 <= row) ? v.w * inv : 0.f;
    }
    *(float4*)(base + c0) = v;
  }
}

// ---------------- launch ----------------
extern "C" void kernel_launch(void* const* d_in, const int* in_sizes, int n_in,
                              void* d_out, int out_size, void* d_ws, size_t ws_size,
                              hipStream_t stream) {
  const float* hs   = (const float*)d_in[0];
  const float* cosb = (const float*)d_in[1];
  const float* sinb = (const float*)d_in[2];
  // d_in[3] attention_mask: recomputed causally in-kernel
  const float* Wq = (const float*)d_in[4];
  const float* Wk = (const float*)d_in[5];
  const float* Wv = (const float*)d_in[6];
  const float* Wo = (const float*)d_in[7];
  const float* qw = (const float*)d_in[8];
  const float* kw = (const float*)d_in[9];

  char* ws = (char*)d_ws;
  bf16_t* qb    = (bf16_t*)(ws + 0);            // 33,554,432  (B,NH,S,HD)
  bf16_t* kb    = (bf16_t*)(ws + 33554432);     // 16,777,216  (B,NKV,S,HD)
  bf16_t* vt    = (bf16_t*)(ws + 50331648);     // 16,777,216  (B,NKV,HD,S)
  bf16_t* ctx   = (bf16_t*)(ws + 67108864);     // 33,554,432  (B,S,NH*HD)
  float*  linv  = (float*)(ws + 100663296);     //    262,144  (B*NH*S)
  float*  knorm = (float*)(ws + 100925440);     //    131,072  (B*NKV*S)
  float*  km    = (float*)(ws + 101056512);     //         64  (B*NKV)

  float* out      = (float*)d_out;
  float* attn_out = out;                            // (B,S,HID) f32
  float* weights  = out + (size_t)B_ * S_ * HID_;   // (B,NH,S,S) f32

  const int M = B_ * S_;  // 4096

  // 1) projections
  gemm_f32w<1><<<dim3(DQ_ / 128, M / 128), 256, 0, stream>>>(hs, Wq, qb, M, DQ_, HID_, NH_);
  gemm_f32w<1><<<dim3(DKV_ / 128, M / 128), 256, 0, stream>>>(hs, Wk, kb, M, DKV_, HID_, NKV_);
  gemm_f32w<2><<<dim3(DKV_ / 128, M / 128), 256, 0, stream>>>(hs, Wv, vt, M, DKV_, HID_, NKV_);

  // 2) norm + rope (in place); K pass also stores per-row |k|^2 (no atomics)
  normrope_kernel<4><<<(B_ * S_ * NH_) / 4, 256, 0, stream>>>(qb, qw, cosb, sinb, nullptr);
  normrope_kernel<3><<<(B_ * S_ * NKV_) / 4, 256, 0, stream>>>(kb, kw, cosb, sinb, knorm);
  kmax_reduce_kernel<<<B_ * NKV_, 256, 0, stream>>>(knorm, km);

  // 3) single-pass attention (unnormalized p-tilde into weights buffer)
  attn1p_kernel<<<dim3(S_ / 64, B_ * NH_), 256, 0, stream>>>(qb, kb, vt, km, weights, linv, ctx);

  // 4) weights normalization + upper-triangle zeros
  wscale_kernel<<<(B_ * NH_ * S_) / 4, 256, 0, stream>>>(weights, linv);

  // 5) output projection -> d_out (f32)
  gemm_f32w<0><<<dim3(HID_ / 128, M / 128), 256, 0, stream>>>(ctx, Wo, attn_out, M, HID_, DQ_, 0);
}

// Round 8
// 1124.024 us; speedup vs baseline: 1.8029x; 1.2381x over previous
//
#include <hip/hip_runtime.h>

// ---------------- problem constants ----------------
#define B_    2
#define S_    2048
#define HID_  3584
#define NH_   16
#define NKV_  8
#define HD_   256
#define DQ_   (NH_ * HD_)    // 4096
#define DKV_  (NKV_ * HD_)   // 2048

static constexpr float SCALE_ = 0.0625f;   // 256^-0.5

typedef __bf16 bf16_t;
typedef __bf16 bf16x8 __attribute__((ext_vector_type(8)));
typedef __bf16 bf16x4 __attribute__((ext_vector_type(4)));
typedef float  f32x4  __attribute__((ext_vector_type(4)));

// ---------------- f32 -> bf16 convert ----------------
__global__ __launch_bounds__(256) void cvt_kernel(const float* __restrict__ in,
                                                  bf16_t* __restrict__ out, int n4) {
  int i = blockIdx.x * 256 + threadIdx.x;
  if (i < n4) {
    float4 v = ((const float4*)in)[i];
    bf16x4 o;
    o[0] = (bf16_t)v.x; o[1] = (bf16_t)v.y; o[2] = (bf16_t)v.z; o[3] = (bf16_t)v.w;
    ((bf16x4*)out)[i] = o;
  }
}

// ---------------- async global->LDS, 16B per lane ----------------
__device__ inline void gload_lds16(const bf16_t* g, bf16_t* l) {
  __builtin_amdgcn_global_load_lds(
      (const __attribute__((address_space(1))) void*)g,
      (__attribute__((address_space(3))) void*)l, 16, 0, 0);
}

// ---------------- GEMM (m97 structure): C[m][n] = sum_k A[m][k]*Bt[n][k], both bf16 ----------------
// 128x128 tile, BK=32, 256 threads (4 waves, each 64x64 = 4x4 frags of 16x16x32).
// Staging: global_load_lds dwordx4, linear LDS [128][32] (wave-uniform base + lane*16).
// MODE 0: OUT f32, plain row-major [M][N]          (o-proj -> d_out)
// MODE 1: OUT bf16, relayout to (B, nh, S, HD)     (Q, K projections)
// MODE 2: OUT bf16, transpose to (B, NKV, HD, S)   (V projection)
template<int MODE>
__global__ __launch_bounds__(256) void gemm_lds(const bf16_t* __restrict__ A,
                                                const bf16_t* __restrict__ Bt,
                                                void* __restrict__ outv,
                                                int M, int N, int K, int nh) {
  __shared__ __align__(16) bf16_t As[128 * 32];
  __shared__ __align__(16) bf16_t Bs[128 * 32];
  const int t = threadIdx.x;
  const int lane = t & 63, wv = t >> 6;
  const int wr = wv >> 1, wc = wv & 1;
  const int lr = lane & 15, lg = lane >> 4;
  const size_t m0 = (size_t)blockIdx.y * 128, n0 = (size_t)blockIdx.x * 128;

  // staging geometry: issue covers 16 rows (4 lanes/row, 8 bf16 each)
  const int srow = wv * 32 + (lane >> 2);
  const int scol = (lane & 3) * 8;
  const bf16_t* ga0 = A  + (m0 + srow) * (size_t)K + scol;
  const bf16_t* gb0 = Bt + (n0 + srow) * (size_t)K + scol;
  bf16_t* la0 = &As[wv * 1024];        // wave-uniform LDS bases
  bf16_t* la1 = &As[wv * 1024 + 512];
  bf16_t* lb0 = &Bs[wv * 1024];
  bf16_t* lb1 = &Bs[wv * 1024 + 512];
  const size_t k16 = 16 * (size_t)K;

  f32x4 acc[4][4] = {};
  for (int k0 = 0; k0 < K; k0 += 32) {
    __syncthreads();                    // prev iter's LDS reads done
    gload_lds16(ga0 + k0,       la0);
    gload_lds16(ga0 + k16 + k0, la1);
    gload_lds16(gb0 + k0,       lb0);
    gload_lds16(gb0 + k16 + k0, lb1);
    __syncthreads();                    // vmcnt(0) drained -> tiles in LDS

    bf16x8 af[4], bfr[4];
#pragma unroll
    for (int i = 0; i < 4; ++i) af[i]  = *(const bf16x8*)&As[(wr * 64 + i * 16 + lr) * 32 + lg * 8];
#pragma unroll
    for (int j = 0; j < 4; ++j) bfr[j] = *(const bf16x8*)&Bs[(wc * 64 + j * 16 + lr) * 32 + lg * 8];
#pragma unroll
    for (int i = 0; i < 4; ++i)
#pragma unroll
      for (int j = 0; j < 4; ++j)
        acc[i][j] = __builtin_amdgcn_mfma_f32_16x16x32_bf16(af[i], bfr[j], acc[i][j], 0, 0, 0);
  }
  // epilogue: C/D layout col=lane&15, row=(lane>>4)*4+reg
#pragma unroll
  for (int i = 0; i < 4; ++i)
#pragma unroll
    for (int j = 0; j < 4; ++j) {
      const int row0 = (int)m0 + wr * 64 + i * 16 + lg * 4;
      const int col  = (int)n0 + wc * 64 + j * 16 + lr;
#pragma unroll
      for (int r = 0; r < 4; ++r) {
        const int row = row0 + r;
        if (MODE == 0) {
          ((float*)outv)[(size_t)row * N + col] = acc[i][j][r];
        } else {
          bf16_t* out = (bf16_t*)outv;
          const bf16_t val = (bf16_t)acc[i][j][r];
          const int b = row >> 11, s = row & (S_ - 1);
          const int h = col >> 8,  hd = col & (HD_ - 1);
          if (MODE == 1) out[((size_t)(b * nh + h) * S_ + s) * HD_ + hd] = val;
          else           out[((size_t)(b * NKV_ + h) * HD_ + hd) * S_ + s] = val;
        }
      }
    }
}

// ---------------- fused RMSNorm + RoPE (in place), (b, s, h) block order ----------------
// optional knorm: per-row |x|^2 after norm (plain store, no atomics)
template<int LOGNH>
__global__ __launch_bounds__(256) void normrope_kernel(bf16_t* __restrict__ x,
                                                       const float* __restrict__ w,
                                                       const float* __restrict__ cosb,
                                                       const float* __restrict__ sinb,
                                                       float* __restrict__ knorm) {
  const int gid  = blockIdx.x * 4 + (threadIdx.x >> 6);  // (b, s, h) order: h innermost
  const int lane = threadIdx.x & 63;
  const int nh = 1 << LOGNH;
  const int h  = gid & (nh - 1);
  const int bs = gid >> LOGNH;                 // b*S + s
  const int b  = bs >> 11, s = bs & (S_ - 1);
  const int rowi = (b * nh + h) * S_ + s;      // row in x's (B, nh, S) layout

  bf16_t* ptr = x + (size_t)rowi * HD_ + lane * 4;
  bf16x4 xv = *(const bf16x4*)ptr;
  float v0 = (float)xv[0], v1 = (float)xv[1], v2 = (float)xv[2], v3 = (float)xv[3];
  float ss = v0 * v0 + v1 * v1 + v2 * v2 + v3 * v3;
#pragma unroll
  for (int off = 1; off < 64; off <<= 1) ss += __shfl_xor(ss, off);
  float r = rsqrtf(ss * (1.0f / HD_) + 1e-6f);

  float4 wv = *(const float4*)(w + lane * 4);
  float x0 = v0 * r * (1.0f + wv.x);
  float x1 = v1 * r * (1.0f + wv.y);
  float x2 = v2 * r * (1.0f + wv.z);
  float x3 = v3 * r * (1.0f + wv.w);

  if (knorm != nullptr) {   // row norm^2 (RoPE rotates pairs: norm preserved)
    float s2 = x0 * x0 + x1 * x1 + x2 * x2 + x3 * x3;
#pragma unroll
    for (int off = 1; off < 64; off <<= 1) s2 += __shfl_xor(s2, off);
    if (lane == 0) knorm[rowi] = s2;
  }

  // rotate_half: dim d pairs with d +/- 128 -> lane ^ 32
  float p0 = __shfl_xor(x0, 32);
  float p1 = __shfl_xor(x1, 32);
  float p2 = __shfl_xor(x2, 32);
  float p3 = __shfl_xor(x3, 32);
  float sgn = (lane < 32) ? -1.0f : 1.0f;

  float4 c  = *(const float4*)(cosb + (size_t)bs * HD_ + lane * 4);
  float4 sn = *(const float4*)(sinb + (size_t)bs * HD_ + lane * 4);
  bf16x4 o;
  o[0] = (bf16_t)(x0 * c.x + sgn * p0 * sn.x);
  o[1] = (bf16_t)(x1 * c.y + sgn * p1 * sn.y);
  o[2] = (bf16_t)(x2 * c.z + sgn * p2 * sn.z);
  o[3] = (bf16_t)(x3 * c.w + sgn * p3 * sn.w);
  *(bf16x4*)ptr = o;
}

// ---------------- per-(b,kv-head) max of knorm ----------------
__global__ __launch_bounds__(256) void kmax_reduce_kernel(const float* __restrict__ knorm,
                                                          float* __restrict__ km) {
  __shared__ float red[4];
  const int t = threadIdx.x;
  const float* src = knorm + (size_t)blockIdx.x * S_;
  float m = 0.0f;
  for (int i = t; i < S_; i += 256) m = fmaxf(m, src[i]);
#pragma unroll
  for (int off = 1; off < 64; off <<= 1) m = fmaxf(m, __shfl_xor(m, off));
  if ((t & 63) == 0) red[t >> 6] = m;
  __syncthreads();
  if (t == 0) km[blockIdx.x] = fmaxf(fmaxf(red[0], red[1]), fmaxf(red[2], red[3]));
}

// ---------------- single-pass flash attention, 4 waves x 16 q-rows, bound-based softmax ----------------
__global__ __launch_bounds__(256) void attn1p_kernel(const bf16_t* __restrict__ qb,
                                                     const bf16_t* __restrict__ kb,
                                                     const bf16_t* __restrict__ vt,
                                                     const float* __restrict__ kmaxbuf,
                                                     float* __restrict__ wout,
                                                     float* __restrict__ linv,
                                                     bf16_t* __restrict__ ctx) {
  __shared__ __align__(16) bf16_t Ks[32][264];      // +8 pad
  __shared__ __align__(16) bf16_t Vs[256][40];      // d-major, +8 pad
  __shared__ __align__(16) bf16_t p_lds[4][16][40];
  __shared__ float qn_lds[4][16];

  const int t = threadIdx.x, w = t >> 6, lane = t & 63;
  const int lr = lane & 15, lg = lane >> 4, rloc = lg * 4;
  const int q0b = blockIdx.x * 64;
  const int q0  = q0b + w * 16;                 // this wave's q-row base
  const int bh = blockIdx.y, b = bh >> 4, h = bh & 15, kvh = h >> 1;

  // Q tile (16 x 256) as 8 A-fragments
  const bf16_t* qptr = qb + ((size_t)(b * NH_ + h) * S_ + q0 + lr) * HD_ + lg * 8;
  bf16x8 qf[8];
#pragma unroll
  for (int c = 0; c < 8; ++c) qf[c] = *(const bf16x8*)(qptr + c * 32);

  // |q_row|^2 for row lr -> transpose to accumulator-row order via LDS
  float qn = 0.0f;
#pragma unroll
  for (int c = 0; c < 8; ++c)
#pragma unroll
    for (int e = 0; e < 8; ++e) { float v = (float)qf[c][e]; qn += v * v; }
  qn += __shfl_xor(qn, 16);
  qn += __shfl_xor(qn, 32);
  if (lg == 0) qn_lds[w][lr] = qn;
  __syncthreads();
  const float kmax2 = kmaxbuf[b * NKV_ + kvh];
  float mb[4];
#pragma unroll
  for (int r = 0; r < 4; ++r)
    mb[r] = SCALE_ * sqrtf(qn_lds[w][rloc + r] * kmax2) + 1.0f;  // >= any score, with margin

  float l[4] = {0.f, 0.f, 0.f, 0.f};
  f32x4 oacc[16] = {};
  const int nkt = (q0b + 64) >> 5;
  float* wrow = wout + ((size_t)bh * S_ + q0) * S_;
  const bf16_t* kgb = kb + (size_t)(b * NKV_ + kvh) * S_ * HD_;
  const bf16_t* vgb = vt + (size_t)(b * NKV_ + kvh) * HD_ * S_;

  const int s_st = t >> 3, c_st = (t & 7) * 32;   // K staging: row s_st, 32 cols
  const int vd   = t >> 3, vc   = (t & 7) * 4;    // V staging: rows vd+32i, 4 cols

  for (int kt = 0; kt < nkt; ++kt) {
    const int colb = kt * 32;
    __syncthreads();   // previous tile's LDS reads complete
    {  // stage K tile (32 x 256) coalesced
      const bf16_t* src = kgb + (size_t)(colb + s_st) * HD_ + c_st;
      bf16x8 k0 = *(const bf16x8*)(src);
      bf16x8 k1 = *(const bf16x8*)(src + 8);
      bf16x8 k2 = *(const bf16x8*)(src + 16);
      bf16x8 k3 = *(const bf16x8*)(src + 24);
      *(bf16x8*)&Ks[s_st][c_st]      = k0;
      *(bf16x8*)&Ks[s_st][c_st + 8]  = k1;
      *(bf16x8*)&Ks[s_st][c_st + 16] = k2;
      *(bf16x8*)&Ks[s_st][c_st + 24] = k3;
    }
#pragma unroll
    for (int i = 0; i < 8; ++i) {  // stage V tile (256 d x 32 s) from vt
      const int d = vd + i * 32;
      bf16x4 vv = *(const bf16x4*)(vgb + (size_t)d * S_ + colb + vc);
      *(bf16x4*)&Vs[d][vc] = vv;
    }
    __syncthreads();

    if (colb <= q0 + 15) {   // wave active for this tile
      f32x4 s0 = {0.f, 0.f, 0.f, 0.f}, s1 = {0.f, 0.f, 0.f, 0.f};
#pragma unroll
      for (int c = 0; c < 8; ++c) {
        bf16x8 k0 = *(const bf16x8*)&Ks[lr][c * 32 + lg * 8];
        bf16x8 k1 = *(const bf16x8*)&Ks[16 + lr][c * 32 + lg * 8];
        s0 = __builtin_amdgcn_mfma_f32_16x16x32_bf16(qf[c], k0, s0, 0, 0, 0);
        s1 = __builtin_amdgcn_mfma_f32_16x16x32_bf16(qf[c], k1, s1, 0, 0, 0);
      }
      const int col0 = colb + lr, col1 = col0 + 16;
#pragma unroll
      for (int r = 0; r < 4; ++r) {
        const int row = q0 + rloc + r;
        const float pa = (col0 <= row) ? __expf(s0[r] * SCALE_ - mb[r]) : 0.0f;
        const float pb = (col1 <= row) ? __expf(s1[r] * SCALE_ - mb[r]) : 0.0f;
        l[r] += pa + pb;
        wrow[(size_t)(rloc + r) * S_ + col0] = pa;
        wrow[(size_t)(rloc + r) * S_ + col1] = pb;
        p_lds[w][rloc + r][lr]      = (bf16_t)pa;
        p_lds[w][rloc + r][lr + 16] = (bf16_t)pb;
      }
      bf16x8 pf = *(const bf16x8*)&p_lds[w][lr][lg * 8];   // P as A-fragment
#pragma unroll
      for (int df = 0; df < 16; ++df) {
        bf16x8 vf = *(const bf16x8*)&Vs[df * 16 + lr][lg * 8];
        oacc[df] = __builtin_amdgcn_mfma_f32_16x16x32_bf16(pf, vf, oacc[df], 0, 0, 0);
      }
    }
  }
  // row sum l: reduce across lr lanes (same lg)
#pragma unroll
  for (int r = 0; r < 4; ++r) {
    l[r] += __shfl_xor(l[r], 1);
    l[r] += __shfl_xor(l[r], 2);
    l[r] += __shfl_xor(l[r], 4);
    l[r] += __shfl_xor(l[r], 8);
  }
  float invl[4];
#pragma unroll
  for (int r = 0; r < 4; ++r) invl[r] = 1.0f / l[r];

  bf16_t* cp = ctx + ((size_t)b * S_ + q0) * DQ_ + h * HD_;
#pragma unroll
  for (int df = 0; df < 16; ++df)
#pragma unroll
    for (int r = 0; r < 4; ++r)
      cp[(size_t)(rloc + r) * DQ_ + df * 16 + lr] = (bf16_t)(oacc[df][r] * invl[r]);

  if (lr == 0) {
#pragma unroll
    for (int r = 0; r < 4; ++r) linv[(size_t)bh * S_ + q0 + rloc + r] = invl[r];
  }
}

// ---------------- weights post-pass: scale lower triangle by 1/l, zero upper ----------------
__global__ __launch_bounds__(256) void wscale_kernel(float* __restrict__ wbuf,
                                                     const float* __restrict__ linv) {
  const int wv = threadIdx.x >> 6, lane = threadIdx.x & 63;
  const size_t rg = (size_t)blockIdx.x * 4 + wv;     // global row in (B*NH, S)
  const int row = (int)(rg & (S_ - 1));
  const float inv = linv[rg];
  float* base = wbuf + rg * S_;
#pragma unroll
  for (int i = 0; i < 8; ++i) {
    const int c0 = (i * 64 + lane) * 4;
    float4 v;
    if (c0 > row) {
      v = make_float4(0.f, 0.f, 0.f, 0.f);
    } else {
      v = *(const float4*)(base + c0);
      v.x = (c0 + 0 <= row) ? v.x * inv : 0.f;
      v.y = (c0 + 1 <= row) ? v.y * inv : 0.f;
      v.z = (c0 + 2 <= row) ? v.z * inv : 0.f;
      v.w = (c0 + 3 <= row) ? v.w * inv : 0.f;
    }
    *(float4*)(base + c0) = v;
  }
}

// ---------------- launch ----------------
extern "C" void kernel_launch(void* const* d_in, const int* in_sizes, int n_in,
                              void* d_out, int out_size, void* d_ws, size_t ws_size,
                              hipStream_t stream) {
  const float* hs   = (const float*)d_in[0];
  const float* cosb = (const float*)d_in[1];
  const float* sinb = (const float*)d_in[2];
  // d_in[3] attention_mask: recomputed causally in-kernel
  const float* Wq = (const float*)d_in[4];
  const float* Wk = (const float*)d_in[5];
  const float* Wv = (const float*)d_in[6];
  const float* Wo = (const float*)d_in[7];
  const float* qw = (const float*)d_in[8];
  const float* kw = (const float*)d_in[9];

  char* ws = (char*)d_ws;
  bf16_t* qb    = (bf16_t*)(ws + 0);            // 33,554,432  (B,NH,S,HD)
  bf16_t* kb    = (bf16_t*)(ws + 33554432);     // 16,777,216  (B,NKV,S,HD)
  bf16_t* vt    = (bf16_t*)(ws + 50331648);     // 16,777,216  (B,NKV,HD,S)
  bf16_t* ctx   = (bf16_t*)(ws + 67108864);     // 33,554,432  (B,S,NH*HD)
  float*  linv  = (float*)(ws + 100663296);     //    262,144
  float*  knorm = (float*)(ws + 100925440);     //    131,072
  float*  km    = (float*)(ws + 101056512);     //        128
  bf16_t* hsb   = (bf16_t*)(ws + 101056640);    // 29,360,128  (B*S, HID) bf16
  bf16_t* wqb   = (bf16_t*)(ws + 130416768);    // 29,360,128
  bf16_t* wkb   = (bf16_t*)(ws + 159776896);    // 14,680,064
  bf16_t* wvb   = (bf16_t*)(ws + 174456960);    // 14,680,064
  bf16_t* wob   = (bf16_t*)(ws + 189137024);    // 29,360,128  -> total 218,497,152

  float* out      = (float*)d_out;
  float* attn_out = out;                            // (B,S,HID) f32
  float* weights  = out + (size_t)B_ * S_ * HID_;   // (B,NH,S,S) f32

  const int M = B_ * S_;  // 4096

  // 0) one-shot bf16 conversion of activations + weights
  cvt_kernel<<<14336, 256, 0, stream>>>(hs, hsb, (B_ * S_ * HID_) / 4);
  cvt_kernel<<<14336, 256, 0, stream>>>(Wq, wqb, (DQ_ * HID_) / 4);
  cvt_kernel<<<7168,  256, 0, stream>>>(Wk, wkb, (DKV_ * HID_) / 4);
  cvt_kernel<<<7168,  256, 0, stream>>>(Wv, wvb, (DKV_ * HID_) / 4);
  cvt_kernel<<<14336, 256, 0, stream>>>(Wo, wob, (HID_ * DQ_) / 4);

  // 1) projections (bf16 x bf16, global_load_lds staging)
  gemm_lds<1><<<dim3(DQ_ / 128, M / 128), 256, 0, stream>>>(hsb, wqb, qb, M, DQ_, HID_, NH_);
  gemm_lds<1><<<dim3(DKV_ / 128, M / 128), 256, 0, stream>>>(hsb, wkb, kb, M, DKV_, HID_, NKV_);
  gemm_lds<2><<<dim3(DKV_ / 128, M / 128), 256, 0, stream>>>(hsb, wvb, vt, M, DKV_, HID_, NKV_);

  // 2) norm + rope (in place); K pass also stores per-row |k|^2
  normrope_kernel<4><<<(B_ * S_ * NH_) / 4, 256, 0, stream>>>(qb, qw, cosb, sinb, nullptr);
  normrope_kernel<3><<<(B_ * S_ * NKV_) / 4, 256, 0, stream>>>(kb, kw, cosb, sinb, knorm);
  kmax_reduce_kernel<<<B_ * NKV_, 256, 0, stream>>>(knorm, km);

  // 3) single-pass attention (unnormalized p-tilde into weights buffer)
  attn1p_kernel<<<dim3(S_ / 64, B_ * NH_), 256, 0, stream>>>(qb, kb, vt, km, weights, linv, ctx);

  // 4) weights normalization + upper-triangle zeros
  wscale_kernel<<<(B_ * NH_ * S_) / 4, 256, 0, stream>>>(weights, linv);

  // 5) output projection -> d_out (f32)
  gemm_lds<0><<<dim3(HID_ / 128, M / 128), 256, 0, stream>>>(ctx, wob, attn_out, M, HID_, DQ_, 0);
}